// Round 2
// baseline (1084.214 us; speedup 1.0000x reference)
//
#include <hip/hip_runtime.h>

#define T_SEQ 4096
#define H_NUM 12
#define HD    64
#define C_DIM 768
#define N_QKV 2304
#define HT    (T_SEQ * HD)   // per-head elements = 262144
#define NSPLIT 2
#define KT_PER (T_SEQ / 64 / NSPLIT)   // 32 k-tiles per split block

typedef float    f32x4 __attribute__((ext_vector_type(4)));
typedef _Float16 half8 __attribute__((ext_vector_type(8)));
typedef _Float16 half4 __attribute__((ext_vector_type(4)));
typedef _Float16 half2v __attribute__((ext_vector_type(2)));
typedef __fp16   fp16x2 __attribute__((ext_vector_type(2)));
typedef unsigned uint4v __attribute__((ext_vector_type(4)));

// async global->LDS, 16B/lane, dest = wave-uniform base + lane*16
#define GLDS(gp, lp) __builtin_amdgcn_global_load_lds( \
    (const __attribute__((address_space(1))) void*)(gp), \
    (__attribute__((address_space(3))) void*)(lp), 16, 0, 0)

// dual-update lane swaps (gfx950): a'[32:63]=b[0:31], b'[0:31]=a[32:63]
__device__ __forceinline__ void permlane32_swap(unsigned& a, unsigned& b) {
    asm("v_permlane32_swap_b32 %0, %1" : "+v"(a), "+v"(b));
}
// a[16:31]<->b[0:15], a[48:63]<->b[32:47]
__device__ __forceinline__ void permlane16_swap(unsigned& a, unsigned& b) {
    asm("v_permlane16_swap_b32 %0, %1" : "+v"(a), "+v"(b));
}

// ---------------------------------------------------------------------------
// split x (fp32) -> xhi + xlo (f16 planes)
// ---------------------------------------------------------------------------
__global__ __launch_bounds__(256) void split_x_kernel(
    const float* __restrict__ x, _Float16* __restrict__ xh,
    _Float16* __restrict__ xl, int n4)
{
    const int i = blockIdx.x * 256 + threadIdx.x;
    if (i >= n4) return;
    const float4 v = ((const float4*)x)[i];
    const float vv[4] = {v.x, v.y, v.z, v.w};
    half4 h, l;
    #pragma unroll
    for (int j = 0; j < 4; ++j) {
        const _Float16 hh = (_Float16)vv[j];
        h[j] = hh;
        l[j] = (_Float16)(vv[j] - (float)hh);
    }
    ((half4*)xh)[i] = h;
    ((half4*)xl)[i] = l;
}

// ---------------------------------------------------------------------------
// transpose+split w_attn [768][2304] -> wthi/wtlo [2304][768] (f16)
// ---------------------------------------------------------------------------
__global__ __launch_bounds__(256) void split_wt_kernel(
    const float* __restrict__ W, _Float16* __restrict__ wth,
    _Float16* __restrict__ wtl)
{
    __shared__ float Ws[64][65];
    const int tid = threadIdx.x;
    const int n0 = blockIdx.x * 64, k0 = blockIdx.y * 64;
    const int lr = tid >> 4, lc = (tid & 15) << 2;
    #pragma unroll
    for (int i = 0; i < 4; ++i) {
        const float4 v = *(const float4*)(W + (size_t)(k0 + lr + i * 16) * N_QKV + n0 + lc);
        Ws[lr + i * 16][lc + 0] = v.x; Ws[lr + i * 16][lc + 1] = v.y;
        Ws[lr + i * 16][lc + 2] = v.z; Ws[lr + i * 16][lc + 3] = v.w;
    }
    __syncthreads();
    const int n = tid >> 2, ks = (tid & 3) << 4;
    half8 h0, h1, l0, l1;
    #pragma unroll
    for (int j = 0; j < 8; ++j) {
        const float v = Ws[ks + j][n];
        const _Float16 hh = (_Float16)v;
        h0[j] = hh; l0[j] = (_Float16)(v - (float)hh);
    }
    #pragma unroll
    for (int j = 0; j < 8; ++j) {
        const float v = Ws[ks + 8 + j][n];
        const _Float16 hh = (_Float16)v;
        h1[j] = hh; l1[j] = (_Float16)(v - (float)hh);
    }
    const size_t dst = (size_t)(n0 + n) * C_DIM + k0 + ks;
    *(half8*)(wth + dst) = h0; *(half8*)(wth + dst + 8) = h1;
    *(half8*)(wtl + dst) = l0; *(half8*)(wtl + dst + 8) = l1;
}

// ---------------------------------------------------------------------------
// QKV GEMM via split-f16 MFMA: [4096,768]x[768,2304] in 3 terms
// (AhBh + AhBl + AlBh), fp32 acc. 128m x 64n tile, BK=64, 256 thr.
// LDS staged via global_load_lds with XOR chunk swizzle; epilogue fuses
// bias + l2norm + hi/lo split (q,k) or bias + V transpose (v).
// ---------------------------------------------------------------------------
__global__ __launch_bounds__(256) void gemm_qkv_kernel(
    const _Float16* __restrict__ xh, const _Float16* __restrict__ xl,
    const _Float16* __restrict__ wth, const _Float16* __restrict__ wtl,
    const float* __restrict__ bias,
    _Float16* __restrict__ qhi, _Float16* __restrict__ qlo,
    _Float16* __restrict__ khi, _Float16* __restrict__ klo,
    _Float16* __restrict__ vt)
{
    __shared__ __align__(16) _Float16 AH[128 * 64];
    __shared__ __align__(16) _Float16 AL[128 * 64];
    __shared__ __align__(16) _Float16 BH[64 * 64];
    __shared__ __align__(16) _Float16 BL[64 * 64];
    const int tid = threadIdx.x;
    const int wv = tid >> 6, lane = tid & 63;
    const int fm = lane & 15, fg = lane >> 4;
    const int lrow = lane >> 3;
    const int lcs  = (lane & 7) ^ (lrow & 7);   // swizzled source chunk
    const int bx = blockIdx.x;                  // n-tile (0..35)
    const int m0 = blockIdx.y * 128;

    auto dma_chunk = [&](int c) {
        const int kc0 = c * 64;
        #pragma unroll
        for (int i = 0; i < 12; ++i) {
            const int qidx = wv * 12 + i;
            if (qidx < 16) {
                const int rg = qidx;
                GLDS(xh + (size_t)(m0 + rg * 8 + lrow) * C_DIM + kc0 + lcs * 8, &AH[rg * 512]);
            } else if (qidx < 32) {
                const int rg = qidx - 16;
                GLDS(xl + (size_t)(m0 + rg * 8 + lrow) * C_DIM + kc0 + lcs * 8, &AL[rg * 512]);
            } else if (qidx < 40) {
                const int rg = qidx - 32;
                GLDS(wth + (size_t)(bx * 64 + rg * 8 + lrow) * C_DIM + kc0 + lcs * 8, &BH[rg * 512]);
            } else {
                const int rg = qidx - 40;
                GLDS(wtl + (size_t)(bx * 64 + rg * 8 + lrow) * C_DIM + kc0 + lcs * 8, &BL[rg * 512]);
            }
        }
    };

    f32x4 acc[2][4];
    #pragma unroll
    for (int mt = 0; mt < 2; ++mt)
        #pragma unroll
        for (int ct = 0; ct < 4; ++ct) acc[mt][ct] = (f32x4){0.f, 0.f, 0.f, 0.f};

    const int swz = fm & 7;
    dma_chunk(0);
    #pragma unroll 1
    for (int c = 0; c < C_DIM / 64; ++c) {
        __syncthreads();   // staged chunk c visible (drains DMA vmcnt)
        half8 ah[2][2], al[2][2], bh[4][2], bl[4][2];
        #pragma unroll
        for (int mt = 0; mt < 2; ++mt) {
            const int rb = (wv * 32 + mt * 16 + fm) * 64;
            #pragma unroll
            for (int kc = 0; kc < 2; ++kc) {
                const int cb = ((kc * 4 + fg) ^ swz) * 8;
                ah[mt][kc] = *(const half8*)&AH[rb + cb];
                al[mt][kc] = *(const half8*)&AL[rb + cb];
            }
        }
        #pragma unroll
        for (int ct = 0; ct < 4; ++ct) {
            const int rb = (ct * 16 + fm) * 64;
            #pragma unroll
            for (int kc = 0; kc < 2; ++kc) {
                const int cb = ((kc * 4 + fg) ^ swz) * 8;
                bh[ct][kc] = *(const half8*)&BH[rb + cb];
                bl[ct][kc] = *(const half8*)&BL[rb + cb];
            }
        }
        __syncthreads();   // all waves done reading staging
        if (c + 1 < C_DIM / 64) dma_chunk(c + 1);   // overlaps with MFMAs below
        #pragma unroll
        for (int mt = 0; mt < 2; ++mt)
            #pragma unroll
            for (int ct = 0; ct < 4; ++ct)
                #pragma unroll
                for (int kc = 0; kc < 2; ++kc) {
                    acc[mt][ct] = __builtin_amdgcn_mfma_f32_16x16x32_f16(ah[mt][kc], bh[ct][kc], acc[mt][ct], 0, 0, 0);
                    acc[mt][ct] = __builtin_amdgcn_mfma_f32_16x16x32_f16(ah[mt][kc], bl[ct][kc], acc[mt][ct], 0, 0, 0);
                    acc[mt][ct] = __builtin_amdgcn_mfma_f32_16x16x32_f16(al[mt][kc], bh[ct][kc], acc[mt][ct], 0, 0, 0);
                }
    }

    const int sec = bx / 12, h = bx % 12;
    const size_t hb = (size_t)h * HT;
    float bb[4];
    #pragma unroll
    for (int ct = 0; ct < 4; ++ct) bb[ct] = bias[bx * 64 + ct * 16 + fm];

    if (sec < 2) {
        _Float16* dh = (sec == 0) ? qhi : khi;
        _Float16* dl = (sec == 0) ? qlo : klo;
        #pragma unroll
        for (int mt = 0; mt < 2; ++mt)
            #pragma unroll
            for (int r = 0; r < 4; ++r) {
                float o[4];
                float ss = 0.f;
                #pragma unroll
                for (int ct = 0; ct < 4; ++ct) {
                    o[ct] = acc[mt][ct][r] + bb[ct];
                    ss += o[ct] * o[ct];
                }
                #pragma unroll
                for (int mk = 1; mk < 16; mk <<= 1) ss += __shfl_xor(ss, mk, 16);
                const float invn = 1.0f / fmaxf(sqrtf(ss), 1e-12f);
                const int t = m0 + wv * 32 + mt * 16 + fg * 4 + r;
                const size_t rb = hb + (size_t)t * HD;
                #pragma unroll
                for (int ct = 0; ct < 4; ++ct) {
                    const float v = o[ct] * invn;
                    const _Float16 vh = (_Float16)v;
                    dh[rb + ct * 16 + fm] = vh;
                    dl[rb + ct * 16 + fm] = (_Float16)(v - (float)vh);
                }
            }
    } else {
        #pragma unroll
        for (int mt = 0; mt < 2; ++mt) {
            const int t0 = m0 + wv * 32 + mt * 16 + fg * 4;
            #pragma unroll
            for (int ct = 0; ct < 4; ++ct) {
                half4 pk;
                #pragma unroll
                for (int r = 0; r < 4; ++r) pk[r] = (_Float16)(acc[mt][ct][r] + bb[ct]);
                *(half4*)(vt + hb + (size_t)(ct * 16 + fm) * T_SEQ + t0) = pk;
            }
        }
    }
}

// ---------------------------------------------------------------------------
// Ksum: per head, f32 sum of khat = khi+klo over rows [0, 2048) -> kpref[12][64].
// Feeds the split-K denominator base: cumsum(num)@2048 = q . kpref.
// ---------------------------------------------------------------------------
__global__ __launch_bounds__(256) void ksum_kernel(
    const _Float16* __restrict__ khi, const _Float16* __restrict__ klo,
    float* __restrict__ kpref)
{
    __shared__ float red[32][64];
    const int h = blockIdx.x;
    const int tid = threadIdx.x;
    const int r0 = tid >> 3;          // 0..31 row within 32-row slab
    const int c0 = (tid & 7) * 8;     // d-column base
    const size_t hb = (size_t)h * HT;
    float acc[8] = {0.f, 0.f, 0.f, 0.f, 0.f, 0.f, 0.f, 0.f};
    #pragma unroll 4
    for (int it = 0; it < (KT_PER * 64) / 32; ++it) {   // 64 slabs of 32 rows
        const size_t off = hb + (size_t)(it * 32 + r0) * HD + c0;
        const half8 a = *(const half8*)(khi + off);
        const half8 b = *(const half8*)(klo + off);
        #pragma unroll
        for (int j = 0; j < 8; ++j) acc[j] += (float)a[j] + (float)b[j];
    }
    #pragma unroll
    for (int j = 0; j < 8; ++j) red[r0][c0 + j] = acc[j];
    __syncthreads();
    if (tid < 64) {
        float s = 0.f;
        #pragma unroll
        for (int r = 0; r < 32; ++r) s += red[r][tid];
        kpref[h * HD + tid] = s;
    }
}

// ---------------------------------------------------------------------------
// Fused attention, split-K over blockIdx.z (2 halves of the k range).
// 256 thr / 4 waves; wave wv owns q-rows [wv*16, wv*16+16).
// K hi/lo + V staged in LDS via swizzled global_load_lds (single buffer,
// next-tile DMA issued after frag reads -> overlaps compute).
//   S^T = K.Q^T via 3x split-f16 MFMA; cumsum via 2x shfl_xor butterfly;
//   denominator base for z=1 comes precomputed (q . kpref);
//   att*2^-5 -> f16 packed in-register -> permlane32/16_swap lane-reg
//   transpose -> A-frag for PV MFMA (no LDS round-trip).
// ---------------------------------------------------------------------------
__global__ __launch_bounds__(256, 5) void attn_kernel(
    const _Float16* __restrict__ qhi, const _Float16* __restrict__ qlo,
    const _Float16* __restrict__ khi, const _Float16* __restrict__ klo,
    const _Float16* __restrict__ vt,  const float* __restrict__ kpref,
    _Float16* __restrict__ yp0, _Float16* __restrict__ yp1)
{
    __shared__ __align__(16) _Float16 KH[64 * 64];
    __shared__ __align__(16) _Float16 KL[64 * 64];
    __shared__ __align__(16) _Float16 VS[64 * 64];

    const int tid = threadIdx.x;
    const int wv = tid >> 6, lane = tid & 63;
    const int fm = lane & 15, fg = lane >> 4;
    const int lrow = lane >> 3;
    const int lcs  = (lane & 7) ^ (lrow & 7);
    const int h = blockIdx.y, qt = blockIdx.x, z = blockIdx.z;
    const size_t hb = (size_t)h * HT;

    // Q B-frags, fixed for whole block
    const int q = qt * 64 + wv * 16 + fm;
    half8 qf[2][2];
    #pragma unroll
    for (int kc = 0; kc < 2; ++kc) {
        const size_t off = hb + (size_t)q * HD + kc * 32 + fg * 8;
        qf[0][kc] = *(const half8*)(qhi + off);
        qf[1][kc] = *(const half8*)(qlo + off);
    }

    // denominator base: z=0 starts at 0; z=1 starts at q . sum_{k<2048} khat
    float carry = 0.0f;
    if (z) {
        const float* kp = kpref + h * HD + fg * 16;
        const size_t qoff = hb + (size_t)q * HD + fg * 16;
        const half8 qh0 = *(const half8*)(qhi + qoff);
        const half8 qh1 = *(const half8*)(qhi + qoff + 8);
        const half8 ql0 = *(const half8*)(qlo + qoff);
        const half8 ql1 = *(const half8*)(qlo + qoff + 8);
        float s = 0.f;
        #pragma unroll
        for (int j = 0; j < 8; ++j) {
            s += ((float)qh0[j] + (float)ql0[j]) * kp[j];
            s += ((float)qh1[j] + (float)ql1[j]) * kp[8 + j];
        }
        s += __shfl_xor(s, 16, 64);
        s += __shfl_xor(s, 32, 64);
        carry = s;
    }

    auto dma_tile = [&](int kt) {
        const size_t kb = hb + (size_t)kt * 64 * HD;
        const int vcol = kt * 64;
        #pragma unroll
        for (int i = 0; i < 6; ++i) {
            const int qidx = wv * 6 + i;
            const int rg = qidx & 7;
            if (qidx < 8) {
                GLDS(khi + kb + (size_t)(rg * 8 + lrow) * HD + lcs * 8, &KH[rg * 512]);
            } else if (qidx < 16) {
                GLDS(klo + kb + (size_t)(rg * 8 + lrow) * HD + lcs * 8, &KL[rg * 512]);
            } else {
                GLDS(vt + hb + (size_t)(rg * 8 + lrow) * T_SEQ + vcol + lcs * 8, &VS[rg * 512]);
            }
        }
    };

    f32x4 yacc[4];
    #pragma unroll
    for (int ct = 0; ct < 4; ++ct) yacc[ct] = (f32x4){0.f, 0.f, 0.f, 0.f};
    const int swz = fm & 7;
    const int kt0 = z * KT_PER;

    dma_tile(kt0);
    #pragma unroll 1
    for (int kk = 0; kk < KT_PER; ++kk) {
        const int kt = kt0 + kk;
        __syncthreads();   // staged tile kt visible (drains DMA vmcnt)
        half8 ka[4][2], kl[4][2], vf[4][2];
        #pragma unroll
        for (int kr = 0; kr < 4; ++kr) {
            const int rb = (kr * 16 + fm) * 64;
            #pragma unroll
            for (int kc = 0; kc < 2; ++kc) {
                const int cb = ((kc * 4 + fg) ^ swz) * 8;
                ka[kr][kc] = *(const half8*)&KH[rb + cb];
                kl[kr][kc] = *(const half8*)&KL[rb + cb];
            }
        }
        #pragma unroll
        for (int ct = 0; ct < 4; ++ct) {
            const int rb = (ct * 16 + fm) * 64;
            #pragma unroll
            for (int kc = 0; kc < 2; ++kc)
                vf[ct][kc] = *(const half8*)&VS[rb + (((kc * 4 + fg) ^ swz) * 8)];
        }
        __syncthreads();   // staging free; frags in registers
        if (kk + 1 < KT_PER) dma_tile(kt + 1);   // overlaps compute below

        // S^T = K.Q^T (split-f16, fp32 acc)
        f32x4 sacc[4];
        #pragma unroll
        for (int kr = 0; kr < 4; ++kr) sacc[kr] = (f32x4){0.f, 0.f, 0.f, 0.f};
        #pragma unroll
        for (int kr = 0; kr < 4; ++kr)
            #pragma unroll
            for (int kc = 0; kc < 2; ++kc) {
                sacc[kr] = __builtin_amdgcn_mfma_f32_16x16x32_f16(ka[kr][kc], qf[0][kc], sacc[kr], 0, 0, 0);
                sacc[kr] = __builtin_amdgcn_mfma_f32_16x16x32_f16(ka[kr][kc], qf[1][kc], sacc[kr], 0, 0, 0);
                sacc[kr] = __builtin_amdgcn_mfma_f32_16x16x32_f16(kl[kr][kc], qf[0][kc], sacc[kr], 0, 0, 0);
            }

        // scan: in-lane 4-chain + 2x shfl_xor butterfly (prefix + tile total);
        // att*2^-5 packed to f16 pairs in-register.
        unsigned pk[4][2];
        #pragma unroll
        for (int kr = 0; kr < 4; ++kr) {
            const float s0 = sacc[kr][0], s1 = sacc[kr][1];
            const float s2 = sacc[kr][2], s3 = sacc[kr][3];
            const float p1 = s0 + s1, p2 = p1 + s2, p3 = p2 + s3;
            const float u1 = __shfl_xor(p3, 16, 64);
            const float pair = p3 + u1;
            const float u2 = __shfl_xor(pair, 32, 64);
            const float tot16 = pair + u2;
            const float pref = ((fg & 1) ? u1 : 0.0f) + ((fg & 2) ? u2 : 0.0f);
            const float base = carry + pref;
            carry += tot16;
            const float a0 = s0 * __builtin_amdgcn_rcpf(fmaxf(base + s0, 1e-6f));
            const float a1 = s1 * __builtin_amdgcn_rcpf(fmaxf(base + p1, 1e-6f));
            const float a2 = s2 * __builtin_amdgcn_rcpf(fmaxf(base + p2, 1e-6f));
            const float a3 = s3 * __builtin_amdgcn_rcpf(fmaxf(base + p3, 1e-6f));
            const fp16x2 c0 = __builtin_amdgcn_cvt_pkrtz(a0 * 0.03125f, a1 * 0.03125f);
            const fp16x2 c1 = __builtin_amdgcn_cvt_pkrtz(a2 * 0.03125f, a3 * 0.03125f);
            pk[kr][0] = __builtin_bit_cast(unsigned, c0);
            pk[kr][1] = __builtin_bit_cast(unsigned, c1);
        }

        // lane-reg transpose: sacc C-layout -> PV A-frag layout, in-register.
        // value k-bits (kr1 kr0 fg1 fg0 h): src regs (kr1 kr0 h), lanes (fg1 fg0)
        //                               -> dst regs (kr1 fg0 h), lanes (kr0 fg1)
        // step1 permlane32_swap: reg-bit kr0 <-> lane-bit5 (fg1)
        // step2 permlane16_swap: reg-bit fg1 <-> lane-bit4 (fg0)
        #pragma unroll
        for (int g = 0; g < 2; ++g)
            #pragma unroll
            for (int hh = 0; hh < 2; ++hh) {
                permlane32_swap(pk[g * 2 + 0][hh], pk[g * 2 + 1][hh]);
                permlane16_swap(pk[g * 2 + 0][hh], pk[g * 2 + 1][hh]);
            }

        // Y += att @ V
        #pragma unroll
        for (int kc = 0; kc < 2; ++kc) {
            const uint4v u = {pk[2 * kc][0], pk[2 * kc][1],
                              pk[2 * kc + 1][0], pk[2 * kc + 1][1]};
            const half8 af = __builtin_bit_cast(half8, u);
            #pragma unroll
            for (int ct = 0; ct < 4; ++ct)
                yacc[ct] = __builtin_amdgcn_mfma_f32_16x16x32_f16(af, vf[ct][kc], yacc[ct], 0, 0, 0);
        }
    }

    // epilogue: partial y f16 = y_z * 2^-12 (acc holds y_z*2^-5 -> scale 2^-7)
    _Float16* __restrict__ yp = z ? yp1 : yp0;
    #pragma unroll
    for (int ct = 0; ct < 4; ++ct)
        #pragma unroll
        for (int r = 0; r < 4; ++r) {
            const int t = qt * 64 + wv * 16 + fg * 4 + r;
            yp[(size_t)t * C_DIM + h * HD + ct * 16 + fm] =
                (_Float16)(yacc[ct][r] * 0.0078125f);
        }
}

// ---------------------------------------------------------------------------
// Proj GEMM via f16 MFMA: (yp0+yp1)(f16, *2^-12)[4096,768] @ Wp[768,768] -> fp32
// ---------------------------------------------------------------------------
__global__ __launch_bounds__(256) void gemm_proj_kernel(
    const _Float16* __restrict__ A0, const _Float16* __restrict__ A1,
    const float* __restrict__ W, const float* __restrict__ bias,
    float* __restrict__ out)
{
    __shared__ _Float16 As[64][72];   // [m][k]
    __shared__ _Float16 Bt[64][72];   // [n][k]
    const int tid = threadIdx.x;
    const int w = tid >> 6, lane = tid & 63;
    const int m = lane & 15, g = lane >> 4;
    const int row0 = blockIdx.x << 6, col0 = blockIdx.y << 6;
    const int ar = tid >> 3, ac8 = (tid & 7) << 3;
    const int bn0 = (tid & 15) << 2, bpv = tid >> 4;
    f32x4 acc[4];
    #pragma unroll
    for (int ct = 0; ct < 4; ++ct) acc[ct] = (f32x4){0.f, 0.f, 0.f, 0.f};

    for (int kt = 0; kt < C_DIM; kt += 64) {
        const size_t i0 = (size_t)(row0 + ar) * C_DIM + kt + ac8;
        const size_t i1 = (size_t)(row0 + ar + 32) * C_DIM + kt + ac8;
        half8 av0 = *(const half8*)(A0 + i0) + *(const half8*)(A1 + i0);
        half8 av1 = *(const half8*)(A0 + i1) + *(const half8*)(A1 + i1);
        float4 w0[2], w1[2];
        #pragma unroll
        for (int i = 0; i < 2; ++i) {
            const int k = kt + 2 * (bpv + 16 * i);
            w0[i] = *(const float4*)(W + (size_t)k       * C_DIM + col0 + bn0);
            w1[i] = *(const float4*)(W + (size_t)(k + 1) * C_DIM + col0 + bn0);
        }
        __syncthreads();
        *(half8*)&As[ar][ac8]      = av0;
        *(half8*)&As[ar + 32][ac8] = av1;
        #pragma unroll
        for (int i = 0; i < 2; ++i) {
            const int p = bpv + 16 * i;
            const float a_[4] = {w0[i].x, w0[i].y, w0[i].z, w0[i].w};
            const float b_[4] = {w1[i].x, w1[i].y, w1[i].z, w1[i].w};
            #pragma unroll
            for (int u = 0; u < 4; ++u) {
                half2v pk = {(_Float16)a_[u], (_Float16)b_[u]};
                *(half2v*)&Bt[bn0 + u][2 * p] = pk;
            }
        }
        __syncthreads();
        #pragma unroll
        for (int kc = 0; kc < 2; ++kc) {
            const half8 a = *(half8*)&As[w * 16 + m][kc * 32 + g * 8];
            #pragma unroll
            for (int ct = 0; ct < 4; ++ct) {
                const half8 b = *(half8*)&Bt[ct * 16 + m][kc * 32 + g * 8];
                acc[ct] = __builtin_amdgcn_mfma_f32_16x16x32_f16(a, b, acc[ct], 0, 0, 0);
            }
        }
    }
    #pragma unroll
    for (int ct = 0; ct < 4; ++ct)
        #pragma unroll
        for (int r = 0; r < 4; ++r) {
            const int t = row0 + w * 16 + g * 4 + r;
            const int n = col0 + ct * 16 + m;
            out[(size_t)t * C_DIM + n] = acc[ct][r] * 4096.0f + bias[n];
        }
}

extern "C" void kernel_launch(void* const* d_in, const int* in_sizes, int n_in,
                              void* d_out, int out_size, void* d_ws, size_t ws_size,
                              hipStream_t stream)
{
    const float* x      = (const float*)d_in[0];
    const float* w_attn = (const float*)d_in[1];
    const float* b_attn = (const float*)d_in[2];
    const float* w_proj = (const float*)d_in[3];
    const float* b_proj = (const float*)d_in[4];
    float* out = (float*)d_out;

    const size_t perQK = (size_t)H_NUM * HT;      // 3,145,728
    const size_t perX  = (size_t)T_SEQ * C_DIM;   // 3,145,728
    const size_t perW  = (size_t)N_QKV * C_DIM;   // 1,769,472
    _Float16* base = (_Float16*)d_ws;
    _Float16* xhi  = base;
    _Float16* xlo  = xhi + perX;
    _Float16* wthi = xlo + perX;
    _Float16* wtlo = wthi + perW;
    _Float16* qhi  = wtlo + perW;
    _Float16* qlo  = qhi + perQK;
    _Float16* khi  = qlo + perQK;
    _Float16* klo  = khi + perQK;
    _Float16* vtp  = klo + perQK;
    float*    kpref = (float*)wthi;   // reuse: wthi dead after qkv (3KB needed)
    _Float16* yp0  = xhi;             // reuse: xhi/xlo dead after qkv
    _Float16* yp1  = xlo;

    split_x_kernel<<<(perX / 4 + 255) / 256, 256, 0, stream>>>(x, xhi, xlo, perX / 4);
    split_wt_kernel<<<dim3(N_QKV / 64, C_DIM / 64), 256, 0, stream>>>(w_attn, wthi, wtlo);
    gemm_qkv_kernel<<<dim3(N_QKV / 64, T_SEQ / 128), 256, 0, stream>>>(
        xhi, xlo, wthi, wtlo, b_attn, qhi, qlo, khi, klo, vtp);
    ksum_kernel<<<dim3(H_NUM), 256, 0, stream>>>(khi, klo, kpref);
    attn_kernel<<<dim3(T_SEQ / 64, H_NUM, NSPLIT), 256, 0, stream>>>(
        qhi, qlo, khi, klo, vtp, kpref, yp0, yp1);
    gemm_proj_kernel<<<dim3(T_SEQ / 64, C_DIM / 64), 256, 0, stream>>>(
        yp0, yp1, w_proj, b_proj, out);
}

// Round 4
// 300.566 us; speedup vs baseline: 3.6072x; 3.6072x over previous
//
#include <hip/hip_runtime.h>

#define T_SEQ 4096
#define H_NUM 12
#define HD    64
#define C_DIM 768
#define N_QKV 2304
#define HT    (T_SEQ * HD)   // per-head elements = 262144
#define KT_TOT (T_SEQ / 64)  // 64 k-tiles, walked sequentially (cumsum order!)

typedef float    f32x4 __attribute__((ext_vector_type(4)));
typedef _Float16 half8 __attribute__((ext_vector_type(8)));
typedef _Float16 half4 __attribute__((ext_vector_type(4)));
typedef _Float16 half2v __attribute__((ext_vector_type(2)));
typedef __fp16   fp16x2 __attribute__((ext_vector_type(2)));
typedef unsigned uint4v __attribute__((ext_vector_type(4)));

// async global->LDS, 16B/lane, dest = wave-uniform base + lane*16
#define GLDS(gp, lp) __builtin_amdgcn_global_load_lds( \
    (const __attribute__((address_space(1))) void*)(gp), \
    (__attribute__((address_space(3))) void*)(lp), 16, 0, 0)

// dual-update lane swaps (gfx950): a'[32:63]=b[0:31], b'[0:31]=a[32:63]
__device__ __forceinline__ void permlane32_swap(unsigned& a, unsigned& b) {
    asm("v_permlane32_swap_b32 %0, %1" : "+v"(a), "+v"(b));
}
// a[16:31]<->b[0:15], a[48:63]<->b[32:47]
__device__ __forceinline__ void permlane16_swap(unsigned& a, unsigned& b) {
    asm("v_permlane16_swap_b32 %0, %1" : "+v"(a), "+v"(b));
}

// ---------------------------------------------------------------------------
// split x (fp32) -> xhi + xlo (f16 planes)
// ---------------------------------------------------------------------------
__global__ __launch_bounds__(256) void split_x_kernel(
    const float* __restrict__ x, _Float16* __restrict__ xh,
    _Float16* __restrict__ xl, int n4)
{
    const int i = blockIdx.x * 256 + threadIdx.x;
    if (i >= n4) return;
    const float4 v = ((const float4*)x)[i];
    const float vv[4] = {v.x, v.y, v.z, v.w};
    half4 h, l;
    #pragma unroll
    for (int j = 0; j < 4; ++j) {
        const _Float16 hh = (_Float16)vv[j];
        h[j] = hh;
        l[j] = (_Float16)(vv[j] - (float)hh);
    }
    ((half4*)xh)[i] = h;
    ((half4*)xl)[i] = l;
}

// ---------------------------------------------------------------------------
// transpose+split w_attn [768][2304] -> wthi/wtlo [2304][768] (f16)
// ---------------------------------------------------------------------------
__global__ __launch_bounds__(256) void split_wt_kernel(
    const float* __restrict__ W, _Float16* __restrict__ wth,
    _Float16* __restrict__ wtl)
{
    __shared__ float Ws[64][65];
    const int tid = threadIdx.x;
    const int n0 = blockIdx.x * 64, k0 = blockIdx.y * 64;
    const int lr = tid >> 4, lc = (tid & 15) << 2;
    #pragma unroll
    for (int i = 0; i < 4; ++i) {
        const float4 v = *(const float4*)(W + (size_t)(k0 + lr + i * 16) * N_QKV + n0 + lc);
        Ws[lr + i * 16][lc + 0] = v.x; Ws[lr + i * 16][lc + 1] = v.y;
        Ws[lr + i * 16][lc + 2] = v.z; Ws[lr + i * 16][lc + 3] = v.w;
    }
    __syncthreads();
    const int n = tid >> 2, ks = (tid & 3) << 4;
    half8 h0, h1, l0, l1;
    #pragma unroll
    for (int j = 0; j < 8; ++j) {
        const float v = Ws[ks + j][n];
        const _Float16 hh = (_Float16)v;
        h0[j] = hh; l0[j] = (_Float16)(v - (float)hh);
    }
    #pragma unroll
    for (int j = 0; j < 8; ++j) {
        const float v = Ws[ks + 8 + j][n];
        const _Float16 hh = (_Float16)v;
        h1[j] = hh; l1[j] = (_Float16)(v - (float)hh);
    }
    const size_t dst = (size_t)(n0 + n) * C_DIM + k0 + ks;
    *(half8*)(wth + dst) = h0; *(half8*)(wth + dst + 8) = h1;
    *(half8*)(wtl + dst) = l0; *(half8*)(wtl + dst + 8) = l1;
}

// ---------------------------------------------------------------------------
// QKV GEMM via split-f16 MFMA: [4096,768]x[768,2304] in 3 terms
// (AhBh + AhBl + AlBh), fp32 acc. 128m x 64n tile, BK=64, 256 thr.
// LDS staged via global_load_lds with XOR chunk swizzle; epilogue fuses
// bias + l2norm + hi/lo split (q,k) or bias + V transpose (v).
// ---------------------------------------------------------------------------
__global__ __launch_bounds__(256) void gemm_qkv_kernel(
    const _Float16* __restrict__ xh, const _Float16* __restrict__ xl,
    const _Float16* __restrict__ wth, const _Float16* __restrict__ wtl,
    const float* __restrict__ bias,
    _Float16* __restrict__ qhi, _Float16* __restrict__ qlo,
    _Float16* __restrict__ khi, _Float16* __restrict__ klo,
    _Float16* __restrict__ vt)
{
    __shared__ __align__(16) _Float16 AH[128 * 64];
    __shared__ __align__(16) _Float16 AL[128 * 64];
    __shared__ __align__(16) _Float16 BH[64 * 64];
    __shared__ __align__(16) _Float16 BL[64 * 64];
    const int tid = threadIdx.x;
    const int wv = tid >> 6, lane = tid & 63;
    const int fm = lane & 15, fg = lane >> 4;
    const int lrow = lane >> 3;
    const int lcs  = (lane & 7) ^ (lrow & 7);   // swizzled source chunk
    const int bx = blockIdx.x;                  // n-tile (0..35)
    const int m0 = blockIdx.y * 128;

    auto dma_chunk = [&](int c) {
        const int kc0 = c * 64;
        #pragma unroll
        for (int i = 0; i < 12; ++i) {
            const int qidx = wv * 12 + i;
            if (qidx < 16) {
                const int rg = qidx;
                GLDS(xh + (size_t)(m0 + rg * 8 + lrow) * C_DIM + kc0 + lcs * 8, &AH[rg * 512]);
            } else if (qidx < 32) {
                const int rg = qidx - 16;
                GLDS(xl + (size_t)(m0 + rg * 8 + lrow) * C_DIM + kc0 + lcs * 8, &AL[rg * 512]);
            } else if (qidx < 40) {
                const int rg = qidx - 32;
                GLDS(wth + (size_t)(bx * 64 + rg * 8 + lrow) * C_DIM + kc0 + lcs * 8, &BH[rg * 512]);
            } else {
                const int rg = qidx - 40;
                GLDS(wtl + (size_t)(bx * 64 + rg * 8 + lrow) * C_DIM + kc0 + lcs * 8, &BL[rg * 512]);
            }
        }
    };

    f32x4 acc[2][4];
    #pragma unroll
    for (int mt = 0; mt < 2; ++mt)
        #pragma unroll
        for (int ct = 0; ct < 4; ++ct) acc[mt][ct] = (f32x4){0.f, 0.f, 0.f, 0.f};

    const int swz = fm & 7;
    dma_chunk(0);
    #pragma unroll 1
    for (int c = 0; c < C_DIM / 64; ++c) {
        __syncthreads();   // staged chunk c visible (drains DMA vmcnt)
        half8 ah[2][2], al[2][2], bh[4][2], bl[4][2];
        #pragma unroll
        for (int mt = 0; mt < 2; ++mt) {
            const int rb = (wv * 32 + mt * 16 + fm) * 64;
            #pragma unroll
            for (int kc = 0; kc < 2; ++kc) {
                const int cb = ((kc * 4 + fg) ^ swz) * 8;
                ah[mt][kc] = *(const half8*)&AH[rb + cb];
                al[mt][kc] = *(const half8*)&AL[rb + cb];
            }
        }
        #pragma unroll
        for (int ct = 0; ct < 4; ++ct) {
            const int rb = (ct * 16 + fm) * 64;
            #pragma unroll
            for (int kc = 0; kc < 2; ++kc) {
                const int cb = ((kc * 4 + fg) ^ swz) * 8;
                bh[ct][kc] = *(const half8*)&BH[rb + cb];
                bl[ct][kc] = *(const half8*)&BL[rb + cb];
            }
        }
        __syncthreads();   // all waves done reading staging
        if (c + 1 < C_DIM / 64) dma_chunk(c + 1);   // overlaps with MFMAs below
        #pragma unroll
        for (int mt = 0; mt < 2; ++mt)
            #pragma unroll
            for (int ct = 0; ct < 4; ++ct)
                #pragma unroll
                for (int kc = 0; kc < 2; ++kc) {
                    acc[mt][ct] = __builtin_amdgcn_mfma_f32_16x16x32_f16(ah[mt][kc], bh[ct][kc], acc[mt][ct], 0, 0, 0);
                    acc[mt][ct] = __builtin_amdgcn_mfma_f32_16x16x32_f16(ah[mt][kc], bl[ct][kc], acc[mt][ct], 0, 0, 0);
                    acc[mt][ct] = __builtin_amdgcn_mfma_f32_16x16x32_f16(al[mt][kc], bh[ct][kc], acc[mt][ct], 0, 0, 0);
                }
    }

    const int sec = bx / 12, h = bx % 12;
    const size_t hb = (size_t)h * HT;
    float bb[4];
    #pragma unroll
    for (int ct = 0; ct < 4; ++ct) bb[ct] = bias[bx * 64 + ct * 16 + fm];

    if (sec < 2) {
        _Float16* dh = (sec == 0) ? qhi : khi;
        _Float16* dl = (sec == 0) ? qlo : klo;
        #pragma unroll
        for (int mt = 0; mt < 2; ++mt)
            #pragma unroll
            for (int r = 0; r < 4; ++r) {
                float o[4];
                float ss = 0.f;
                #pragma unroll
                for (int ct = 0; ct < 4; ++ct) {
                    o[ct] = acc[mt][ct][r] + bb[ct];
                    ss += o[ct] * o[ct];
                }
                #pragma unroll
                for (int mk = 1; mk < 16; mk <<= 1) ss += __shfl_xor(ss, mk, 16);
                const float invn = 1.0f / fmaxf(sqrtf(ss), 1e-12f);
                const int t = m0 + wv * 32 + mt * 16 + fg * 4 + r;
                const size_t rb = hb + (size_t)t * HD;
                #pragma unroll
                for (int ct = 0; ct < 4; ++ct) {
                    const float v = o[ct] * invn;
                    const _Float16 vh = (_Float16)v;
                    dh[rb + ct * 16 + fm] = vh;
                    dl[rb + ct * 16 + fm] = (_Float16)(v - (float)vh);
                }
            }
    } else {
        #pragma unroll
        for (int mt = 0; mt < 2; ++mt) {
            const int t0 = m0 + wv * 32 + mt * 16 + fg * 4;
            #pragma unroll
            for (int ct = 0; ct < 4; ++ct) {
                half4 pk;
                #pragma unroll
                for (int r = 0; r < 4; ++r) pk[r] = (_Float16)(acc[mt][ct][r] + bb[ct]);
                *(half4*)(vt + hb + (size_t)(ct * 16 + fm) * T_SEQ + t0) = pk;
            }
        }
    }
}

// ---------------------------------------------------------------------------
// Fused attention. 256 thr / 4 waves; wave wv owns q-rows [wv*16, wv*16+16).
// Sequential k-walk over all 64 tiles (cumsum order == reference order; do
// NOT split-K: the 1e-6 denominator clamp amplifies any reordered summation
// chaotically — split-K failed correctness on codegen-dependent rounding).
// K hi/lo + V double-buffered in LDS via swizzled global_load_lds:
// one barrier per tile; next-tile DMA issued BEFORE frag reads so its
// latency hides under frag reads + full tile compute.
//   S^T = K.Q^T via 3x split-f16 MFMA; cumsum via 2x shfl_xor butterfly;
//   att*2^-5 -> f16 packed in-register -> permlane32/16_swap lane-reg
//   transpose -> A-frag for PV MFMA (no LDS round-trip, no bank conflicts).
// NOTE: no min-waves launch_bounds hint — (256,5) capped VGPR at ~102 and
// spilled the hot-loop frags to scratch (1.9GB writes, 4.5x slower).
// ---------------------------------------------------------------------------
__global__ __launch_bounds__(256) void attn_kernel(
    const _Float16* __restrict__ qhi, const _Float16* __restrict__ qlo,
    const _Float16* __restrict__ khi, const _Float16* __restrict__ klo,
    const _Float16* __restrict__ vt,  _Float16* __restrict__ ylin)
{
    __shared__ __align__(16) _Float16 KH[2][64 * 64];
    __shared__ __align__(16) _Float16 KL[2][64 * 64];
    __shared__ __align__(16) _Float16 VS[2][64 * 64];

    const int tid = threadIdx.x;
    const int wv = tid >> 6, lane = tid & 63;
    const int fm = lane & 15, fg = lane >> 4;
    const int lrow = lane >> 3;
    const int lcs  = (lane & 7) ^ (lrow & 7);
    const int h = blockIdx.y, qt = blockIdx.x;
    const size_t hb = (size_t)h * HT;

    // Q B-frags, fixed for whole block
    const int q = qt * 64 + wv * 16 + fm;
    half8 qf[2][2];
    #pragma unroll
    for (int kc = 0; kc < 2; ++kc) {
        const size_t off = hb + (size_t)q * HD + kc * 32 + fg * 8;
        qf[0][kc] = *(const half8*)(qhi + off);
        qf[1][kc] = *(const half8*)(qlo + off);
    }

    auto dma_tile = [&](int kt, int buf) {
        const size_t kb = hb + (size_t)kt * 64 * HD;
        const int vcol = kt * 64;
        #pragma unroll
        for (int i = 0; i < 6; ++i) {
            const int qidx = wv * 6 + i;
            const int rg = qidx & 7;
            if (qidx < 8) {
                GLDS(khi + kb + (size_t)(rg * 8 + lrow) * HD + lcs * 8, &KH[buf][rg * 512]);
            } else if (qidx < 16) {
                GLDS(klo + kb + (size_t)(rg * 8 + lrow) * HD + lcs * 8, &KL[buf][rg * 512]);
            } else {
                GLDS(vt + hb + (size_t)(rg * 8 + lrow) * T_SEQ + vcol + lcs * 8, &VS[buf][rg * 512]);
            }
        }
    };

    f32x4 yacc[4];
    #pragma unroll
    for (int ct = 0; ct < 4; ++ct) yacc[ct] = (f32x4){0.f, 0.f, 0.f, 0.f};
    float carry = 0.0f;
    const int swz = fm & 7;

    int cur = 0;
    dma_tile(0, 0);
    #pragma unroll 1
    for (int kt = 0; kt < KT_TOT; ++kt) {
        __syncthreads();   // buf[cur] DMA drained; prior reads of buf[cur^1] done
        if (kt + 1 < KT_TOT) dma_tile(kt + 1, cur ^ 1);   // hides under reads+compute

        half8 ka[4][2], kl[4][2], vf[4][2];
        #pragma unroll
        for (int kr = 0; kr < 4; ++kr) {
            const int rb = (kr * 16 + fm) * 64;
            #pragma unroll
            for (int kc = 0; kc < 2; ++kc) {
                const int cb = ((kc * 4 + fg) ^ swz) * 8;
                ka[kr][kc] = *(const half8*)&KH[cur][rb + cb];
                kl[kr][kc] = *(const half8*)&KL[cur][rb + cb];
            }
        }
        #pragma unroll
        for (int ct = 0; ct < 4; ++ct) {
            const int rb = (ct * 16 + fm) * 64;
            #pragma unroll
            for (int kc = 0; kc < 2; ++kc)
                vf[ct][kc] = *(const half8*)&VS[cur][rb + (((kc * 4 + fg) ^ swz) * 8)];
        }

        // S^T = K.Q^T (split-f16, fp32 acc)
        f32x4 sacc[4];
        #pragma unroll
        for (int kr = 0; kr < 4; ++kr) sacc[kr] = (f32x4){0.f, 0.f, 0.f, 0.f};
        #pragma unroll
        for (int kr = 0; kr < 4; ++kr)
            #pragma unroll
            for (int kc = 0; kc < 2; ++kc) {
                sacc[kr] = __builtin_amdgcn_mfma_f32_16x16x32_f16(ka[kr][kc], qf[0][kc], sacc[kr], 0, 0, 0);
                sacc[kr] = __builtin_amdgcn_mfma_f32_16x16x32_f16(ka[kr][kc], qf[1][kc], sacc[kr], 0, 0, 0);
                sacc[kr] = __builtin_amdgcn_mfma_f32_16x16x32_f16(kl[kr][kc], qf[0][kc], sacc[kr], 0, 0, 0);
            }

        // scan: in-lane 4-chain + 2x shfl_xor butterfly (prefix + tile total);
        // att*2^-5 packed to f16 pairs in-register.
        unsigned pk[4][2];
        #pragma unroll
        for (int kr = 0; kr < 4; ++kr) {
            const float s0 = sacc[kr][0], s1 = sacc[kr][1];
            const float s2 = sacc[kr][2], s3 = sacc[kr][3];
            const float p1 = s0 + s1, p2 = p1 + s2, p3 = p2 + s3;
            const float u1 = __shfl_xor(p3, 16, 64);
            const float pair = p3 + u1;
            const float u2 = __shfl_xor(pair, 32, 64);
            const float tot16 = pair + u2;
            const float pref = ((fg & 1) ? u1 : 0.0f) + ((fg & 2) ? u2 : 0.0f);
            const float base = carry + pref;
            carry += tot16;
            const float a0 = s0 * __builtin_amdgcn_rcpf(fmaxf(base + s0, 1e-6f));
            const float a1 = s1 * __builtin_amdgcn_rcpf(fmaxf(base + p1, 1e-6f));
            const float a2 = s2 * __builtin_amdgcn_rcpf(fmaxf(base + p2, 1e-6f));
            const float a3 = s3 * __builtin_amdgcn_rcpf(fmaxf(base + p3, 1e-6f));
            const fp16x2 c0 = __builtin_amdgcn_cvt_pkrtz(a0 * 0.03125f, a1 * 0.03125f);
            const fp16x2 c1 = __builtin_amdgcn_cvt_pkrtz(a2 * 0.03125f, a3 * 0.03125f);
            pk[kr][0] = __builtin_bit_cast(unsigned, c0);
            pk[kr][1] = __builtin_bit_cast(unsigned, c1);
        }

        // lane-reg transpose: sacc C-layout -> PV A-frag layout, in-register.
        // value k-bits (kr1 kr0 fg1 fg0 h): src regs (kr1 kr0 h), lanes (fg1 fg0)
        //                               -> dst regs (kr1 fg0 h), lanes (kr0 fg1)
        // step1 permlane32_swap: reg-bit kr0 <-> lane-bit5 (fg1)
        // step2 permlane16_swap: reg-bit fg1 <-> lane-bit4 (fg0)
        #pragma unroll
        for (int g = 0; g < 2; ++g)
            #pragma unroll
            for (int hh = 0; hh < 2; ++hh) {
                permlane32_swap(pk[g * 2 + 0][hh], pk[g * 2 + 1][hh]);
                permlane16_swap(pk[g * 2 + 0][hh], pk[g * 2 + 1][hh]);
            }

        // Y += att @ V
        #pragma unroll
        for (int kc = 0; kc < 2; ++kc) {
            const uint4v u = {pk[2 * kc][0], pk[2 * kc][1],
                              pk[2 * kc + 1][0], pk[2 * kc + 1][1]};
            const half8 af = __builtin_bit_cast(half8, u);
            #pragma unroll
            for (int ct = 0; ct < 4; ++ct)
                yacc[ct] = __builtin_amdgcn_mfma_f32_16x16x32_f16(af, vf[ct][kc], yacc[ct], 0, 0, 0);
        }
        cur ^= 1;
    }

    // epilogue: ylin f16 = y * 2^-12 (acc holds y*2^-5 -> scale 2^-7)
    #pragma unroll
    for (int ct = 0; ct < 4; ++ct)
        #pragma unroll
        for (int r = 0; r < 4; ++r) {
            const int t = qt * 64 + wv * 16 + fg * 4 + r;
            ylin[(size_t)t * C_DIM + h * HD + ct * 16 + fm] =
                (_Float16)(yacc[ct][r] * 0.0078125f);
        }
}

// ---------------------------------------------------------------------------
// Proj GEMM via f16 MFMA: ylin(f16, *2^-12)[4096,768] @ Wp[768,768] -> out fp32
// ---------------------------------------------------------------------------
__global__ __launch_bounds__(256) void gemm_proj_kernel(
    const _Float16* __restrict__ A, const float* __restrict__ W,
    const float* __restrict__ bias, float* __restrict__ out)
{
    __shared__ _Float16 As[64][72];   // [m][k]
    __shared__ _Float16 Bt[64][72];   // [n][k]
    const int tid = threadIdx.x;
    const int w = tid >> 6, lane = tid & 63;
    const int m = lane & 15, g = lane >> 4;
    const int row0 = blockIdx.x << 6, col0 = blockIdx.y << 6;
    const int ar = tid >> 3, ac8 = (tid & 7) << 3;
    const int bn0 = (tid & 15) << 2, bpv = tid >> 4;
    f32x4 acc[4];
    #pragma unroll
    for (int ct = 0; ct < 4; ++ct) acc[ct] = (f32x4){0.f, 0.f, 0.f, 0.f};

    for (int kt = 0; kt < C_DIM; kt += 64) {
        half8 av0 = *(const half8*)(A + (size_t)(row0 + ar)      * C_DIM + kt + ac8);
        half8 av1 = *(const half8*)(A + (size_t)(row0 + ar + 32) * C_DIM + kt + ac8);
        float4 w0[2], w1[2];
        #pragma unroll
        for (int i = 0; i < 2; ++i) {
            const int k = kt + 2 * (bpv + 16 * i);
            w0[i] = *(const float4*)(W + (size_t)k       * C_DIM + col0 + bn0);
            w1[i] = *(const float4*)(W + (size_t)(k + 1) * C_DIM + col0 + bn0);
        }
        __syncthreads();
        *(half8*)&As[ar][ac8]      = av0;
        *(half8*)&As[ar + 32][ac8] = av1;
        #pragma unroll
        for (int i = 0; i < 2; ++i) {
            const int p = bpv + 16 * i;
            const float a_[4] = {w0[i].x, w0[i].y, w0[i].z, w0[i].w};
            const float b_[4] = {w1[i].x, w1[i].y, w1[i].z, w1[i].w};
            #pragma unroll
            for (int u = 0; u < 4; ++u) {
                half2v pk = {(_Float16)a_[u], (_Float16)b_[u]};
                *(half2v*)&Bt[bn0 + u][2 * p] = pk;
            }
        }
        __syncthreads();
        #pragma unroll
        for (int kc = 0; kc < 2; ++kc) {
            const half8 a = *(half8*)&As[w * 16 + m][kc * 32 + g * 8];
            #pragma unroll
            for (int ct = 0; ct < 4; ++ct) {
                const half8 b = *(half8*)&Bt[ct * 16 + m][kc * 32 + g * 8];
                acc[ct] = __builtin_amdgcn_mfma_f32_16x16x32_f16(a, b, acc[ct], 0, 0, 0);
            }
        }
    }
    #pragma unroll
    for (int ct = 0; ct < 4; ++ct)
        #pragma unroll
        for (int r = 0; r < 4; ++r) {
            const int t = row0 + w * 16 + g * 4 + r;
            const int n = col0 + ct * 16 + m;
            out[(size_t)t * C_DIM + n] = acc[ct][r] * 4096.0f + bias[n];
        }
}

extern "C" void kernel_launch(void* const* d_in, const int* in_sizes, int n_in,
                              void* d_out, int out_size, void* d_ws, size_t ws_size,
                              hipStream_t stream)
{
    const float* x      = (const float*)d_in[0];
    const float* w_attn = (const float*)d_in[1];
    const float* b_attn = (const float*)d_in[2];
    const float* w_proj = (const float*)d_in[3];
    const float* b_proj = (const float*)d_in[4];
    float* out = (float*)d_out;

    const size_t perQK = (size_t)H_NUM * HT;      // 3,145,728
    const size_t perX  = (size_t)T_SEQ * C_DIM;   // 3,145,728
    const size_t perW  = (size_t)N_QKV * C_DIM;   // 1,769,472
    _Float16* base = (_Float16*)d_ws;
    _Float16* xhi  = base;
    _Float16* xlo  = xhi + perX;
    _Float16* wthi = xlo + perX;
    _Float16* wtlo = wthi + perW;
    _Float16* qhi  = wtlo + perW;
    _Float16* qlo  = qhi + perQK;
    _Float16* khi  = qlo + perQK;
    _Float16* klo  = khi + perQK;
    _Float16* vtp  = klo + perQK;
    _Float16* ylin = xhi;                          // reuse: xhi dead after qkv

    split_x_kernel<<<(perX / 4 + 255) / 256, 256, 0, stream>>>(x, xhi, xlo, perX / 4);
    split_wt_kernel<<<dim3(N_QKV / 64, C_DIM / 64), 256, 0, stream>>>(w_attn, wthi, wtlo);
    gemm_qkv_kernel<<<dim3(N_QKV / 64, T_SEQ / 128), 256, 0, stream>>>(
        xhi, xlo, wthi, wtlo, b_attn, qhi, qlo, khi, klo, vtp);
    attn_kernel<<<dim3(T_SEQ / 64, H_NUM), 256, 0, stream>>>(
        qhi, qlo, khi, klo, vtp, ylin);
    gemm_proj_kernel<<<dim3(T_SEQ / 64, C_DIM / 64), 256, 0, stream>>>(
        ylin, w_proj, b_proj, out);
}